// Round 5
// baseline (408.207 us; speedup 1.0000x reference)
//
#include <hip/hip_runtime.h>
#include <hip/hip_bf16.h>

// 2-layer GCN on MI355X.
// R10 = MEASUREMENT ROUND. R6/R8/R9 aggregate rewrites (ILP depth, L2
// chunking, 4-8x wider gathers) were ALL null at ~197us -> my per-kernel
// breakdown is inferred, not measured (everything hides below the 44-47us
// harness fills in top-5). This round: agg1 replicated (4 extra plain, all
// idempotent) + one DOUBLE-GRID replica (~2x agg1 -> tops rocprof, exposing
// the gather kernel's counters). T - base = 6*agg1 + 5*launch_overhead.
// Pre-committed: T~440-480 => agg1~42 (random-line wall; attack build next);
// T~290-340 => agg1~20 (budget is build/overhead; pivot to mega-fusion).
// Safe win kept: convert_weights folded into build grid (-1 dispatch).

#define ELL_CAP 64   // deg ~ Poisson(16); P(deg>=64) ~ 1e-18
#define NPART 8      // = XCD count

typedef __attribute__((ext_vector_type(8))) short short8;   // 8 bf16 (4 VGPRs)
typedef __attribute__((ext_vector_type(4))) float f32x4;

static __device__ __forceinline__ unsigned short f2bf(float f) {
    unsigned int u = __float_as_uint(f);
    u = (u + 0x7fff + ((u >> 16) & 1)) >> 16;   // round-to-nearest-even
    return (unsigned short)u;
}
static __device__ __forceinline__ float2 bfunpack(unsigned int u) {
    return make_float2(__uint_as_float(u << 16),            // low short  = feat 2i
                       __uint_as_float(u & 0xffff0000u));   // high short = feat 2i+1
}

// ---------------- XCD-partitioned ELL build + weight conversion ------------
// blocks [0, grid-1): build (part = bid&7, chunk = bid>>3)
// block  grid-1:      w1t/w2t transpose+bf16 (independent; feeds gemm1 later)

__global__ __launch_bounds__(256) void build_ell_part(
    const int* __restrict__ src, const int* __restrict__ dst,
    int* __restrict__ cnt, unsigned short* __restrict__ ell, int E, int partSize,
    const float* __restrict__ W1, const float* __restrict__ W2,
    short* __restrict__ w1t, short* __restrict__ w2t)
{
    if (blockIdx.x == gridDim.x - 1) {             // ---- weights block ----
        for (int i = threadIdx.x; i < 128 * 128 + 128 * 64; i += 256) {
            if (i < 128 * 128) {
                int k = i >> 7, nn = i & 127;
                w1t[nn * 128 + k] = (short)f2bf(W1[i]);
            } else {
                int j = i - 128 * 128;
                int k = j >> 6, nn = j & 63;
                w2t[nn * 128 + k] = (short)f2bf(W2[j]);
            }
        }
        return;
    }

    const int part   = blockIdx.x & (NPART - 1);   // = XCD under round-robin
    const int chunk  = blockIdx.x >> 3;
    const int nchunk = (gridDim.x - 1) >> 3;
    const int lo = part * partSize, hi = lo + partSize;

    const int  E4  = E >> 2;
    const int  per = (E4 + nchunk - 1) / nchunk;
    const int  i1  = min((chunk + 1) * per, E4);
    const int4* __restrict__ d4p = (const int4*)dst;
    const int4* __restrict__ s4p = (const int4*)src;

    for (int i = chunk * per + threadIdx.x; i < i1; i += 256) {
        int4 d4 = d4p[i];
        int4 s4 = s4p[i];
        if (d4.x >= lo && d4.x < hi) {
            int p = atomicAdd(&cnt[d4.x], 1);
            if (p < ELL_CAP) ell[(size_t)d4.x * ELL_CAP + p] = (unsigned short)s4.x;
        }
        if (d4.y >= lo && d4.y < hi) {
            int p = atomicAdd(&cnt[d4.y], 1);
            if (p < ELL_CAP) ell[(size_t)d4.y * ELL_CAP + p] = (unsigned short)s4.y;
        }
        if (d4.z >= lo && d4.z < hi) {
            int p = atomicAdd(&cnt[d4.z], 1);
            if (p < ELL_CAP) ell[(size_t)d4.z * ELL_CAP + p] = (unsigned short)s4.z;
        }
        if (d4.w >= lo && d4.w < hi) {
            int p = atomicAdd(&cnt[d4.w], 1);
            if (p < ELL_CAP) ell[(size_t)d4.w * ELL_CAP + p] = (unsigned short)s4.w;
        }
    }
    if (chunk == 0) {                              // E % 4 tail
        for (int e = (E & ~3) + threadIdx.x; e < E; e += 256) {
            int d = dst[e];
            if (d >= lo && d < hi) {
                int p = atomicAdd(&cnt[d], 1);
                if (p < ELL_CAP) ell[(size_t)d * ELL_CAP + p] = (unsigned short)src[e];
            }
        }
    }
}

// ---------------- MFMA GEMM: Cb[i][j] = bf16(dinv[i]*(A W)[i][j]), row-major

template<int NC, bool AF32>
__global__ __launch_bounds__(256) void gemm_mfma(
    const void* __restrict__ Av, const short* __restrict__ Bt,
    const int* __restrict__ cnt, unsigned short* __restrict__ Cb, int n)
{
    __shared__ short Bs[NC][136];
    const int tid = threadIdx.x;

    #pragma unroll
    for (int i = 0; i < NC / 16; ++i) {      // NC*128 shorts, 16B per thread/iter
        int idx = tid + i * 256;
        int nrow = idx >> 4;
        int kcol = (idx & 15) * 8;
        *(short8*)&Bs[nrow][kcol] = *(const short8*)(Bt + nrow * 128 + kcol);
    }
    __syncthreads();

    const int wave = tid >> 6, lane = tid & 63;
    const int row0 = blockIdx.x * 64 + wave * 16;
    if (row0 >= n) return;
    const int quad = lane >> 4, l16 = lane & 15;

    short8 af[4];
    if (AF32) {
        const float* arow = (const float*)Av + (size_t)(row0 + l16) * 128 + quad * 8;
        #pragma unroll
        for (int kk = 0; kk < 4; ++kk) {
            float4 u = *(const float4*)(arow + kk * 32);
            float4 v = *(const float4*)(arow + kk * 32 + 4);
            short8 f;
            f[0] = (short)f2bf(u.x); f[1] = (short)f2bf(u.y);
            f[2] = (short)f2bf(u.z); f[3] = (short)f2bf(u.w);
            f[4] = (short)f2bf(v.x); f[5] = (short)f2bf(v.y);
            f[6] = (short)f2bf(v.z); f[7] = (short)f2bf(v.w);
            af[kk] = f;
        }
    } else {
        const short* arow = (const short*)Av + (size_t)(row0 + l16) * 128 + quad * 8;
        #pragma unroll
        for (int kk = 0; kk < 4; ++kk)
            af[kk] = *(const short8*)(arow + kk * 32);
    }

    float dv[4];
    #pragma unroll
    for (int r = 0; r < 4; ++r)
        dv[r] = rsqrtf((float)cnt[row0 + quad * 4 + r] + 1.0f);

    #pragma unroll
    for (int t = 0; t < NC / 16; ++t) {
        f32x4 acc = {0.f, 0.f, 0.f, 0.f};
        #pragma unroll
        for (int kk = 0; kk < 4; ++kk) {
            short8 bfr = *(const short8*)&Bs[t * 16 + l16][kk * 32 + quad * 8];
            acc = __builtin_amdgcn_mfma_f32_16x16x32_bf16(af[kk], bfr, acc, 0, 0, 0);
        }
        #pragma unroll
        for (int r = 0; r < 4; ++r) {
            int gr = row0 + quad * 4 + r;
            Cb[(size_t)gr * NC + t * 16 + l16] = f2bf(acc[r] * dv[r]);
        }
    }
}

// ---------------- wide-gather aggregates (R9 structure) ----------------
// L1: one wave per node, 256B rows, dwordx4 gather = 4 edges/instr.
// nb = logical block count: replicas with grid = 2*nb compute every node
// twice (identical bytes written twice -> benign, exposes counters).

__global__ __launch_bounds__(256) void aggregate_l1(
    const unsigned short* __restrict__ hb,   // [n][128] bf16, dinv-scaled
    const unsigned short* __restrict__ ell,
    const int* __restrict__ cnt, const float* __restrict__ bias,
    unsigned int* __restrict__ z1b, int n, int nb)
{
    int lb = blockIdx.x;
    if (lb >= nb) lb -= nb;                  // double-grid replica wraps
    const int node = lb * 4 + (threadIdx.x >> 6);
    if (node >= n) return;
    const int lane = threadIdx.x & 63;
    const int quad = lane >> 4, l16 = lane & 15;

    int deg = cnt[node];
    const float d = rsqrtf((float)deg + 1.0f);
    if (deg > ELL_CAP) deg = ELL_CAP;
    const unsigned short* __restrict__ row = ell + (size_t)node * ELL_CAP;

    float acc[8];
    {   // self term: counted once (quad 0 only)
        uint4 v = *(const uint4*)(hb + (size_t)node * 128 + l16 * 8);
        bool val = (quad == 0);
        #pragma unroll
        for (int j = 0; j < 4; ++j) {
            float2 f = bfunpack(((const unsigned int*)&v)[j]);
            acc[2 * j]     = val ? f.x : 0.f;
            acc[2 * j + 1] = val ? f.y : 0.f;
        }
    }
    const int degR = (deg + 3) & ~3;
    #pragma unroll 2
    for (int e = 0; e < degR; e += 4) {
        unsigned int w0 = *(const unsigned int*)&row[e];       // edges e,e+1
        unsigned int w1 = *(const unsigned int*)&row[e + 2];   // edges e+2,e+3
        unsigned int hw = (quad & 2) ? w1 : w0;
        int s = (quad & 1) ? (int)(hw >> 16) : (int)(hw & 0xffff);
        s = min(s, n - 1);                                      // poison-safe
        uint4 v = *(const uint4*)(hb + (size_t)s * 128 + l16 * 8);
        bool val = (e + quad < deg);
        #pragma unroll
        for (int j = 0; j < 4; ++j) {
            float2 f = bfunpack(((const unsigned int*)&v)[j]);
            acc[2 * j]     += val ? f.x : 0.f;
            acc[2 * j + 1] += val ? f.y : 0.f;
        }
    }
    #pragma unroll
    for (int j = 0; j < 8; ++j) {            // fold 4 quads
        acc[j] += __shfl_xor(acc[j], 16);
        acc[j] += __shfl_xor(acc[j], 32);
    }
    if (quad == 0) {
        unsigned int ow[4];
        #pragma unroll
        for (int j = 0; j < 4; ++j) {
            float bx = bias[l16 * 8 + 2 * j];
            float by = bias[l16 * 8 + 2 * j + 1];
            float ox = fmaxf(fmaf(acc[2 * j],     d, bx), 0.f);
            float oy = fmaxf(fmaf(acc[2 * j + 1], d, by), 0.f);
            ow[j] = (unsigned int)f2bf(ox) | ((unsigned int)f2bf(oy) << 16);
        }
        *(uint4*)&z1b[(size_t)node * 64 + l16 * 4] = *(const uint4*)ow;
    }
}

// L2: one wave per node, 128B rows, dwordx4 gather = 8 edges/instr.

__global__ __launch_bounds__(256) void aggregate_l2(
    const unsigned short* __restrict__ hb,   // [n][64] bf16, dinv-scaled
    const unsigned short* __restrict__ ell,
    const int* __restrict__ cnt, const float* __restrict__ bias,
    float* __restrict__ out, int n)          // [n][64] fp32
{
    const int node = blockIdx.x * 4 + (threadIdx.x >> 6);
    if (node >= n) return;
    const int lane = threadIdx.x & 63;
    const int oct = lane >> 3, l8 = lane & 7;

    int deg = cnt[node];
    const float d = rsqrtf((float)deg + 1.0f);
    if (deg > ELL_CAP) deg = ELL_CAP;
    const unsigned short* __restrict__ row = ell + (size_t)node * ELL_CAP;

    float acc[8];
    {   // self term (oct 0 only)
        uint4 v = *(const uint4*)(hb + (size_t)node * 64 + l8 * 8);
        bool val = (oct == 0);
        #pragma unroll
        for (int j = 0; j < 4; ++j) {
            float2 f = bfunpack(((const unsigned int*)&v)[j]);
            acc[2 * j]     = val ? f.x : 0.f;
            acc[2 * j + 1] = val ? f.y : 0.f;
        }
    }
    const int degR = (deg + 7) & ~7;
    #pragma unroll 2
    for (int e = 0; e < degR; e += 8) {
        uint4 w = *(const uint4*)&row[e];    // edges e..e+7
        unsigned int pw = (oct & 4) ? ((oct & 2) ? w.w : w.z)
                                    : ((oct & 2) ? w.y : w.x);
        int s = (oct & 1) ? (int)(pw >> 16) : (int)(pw & 0xffff);
        s = min(s, n - 1);                   // poison-safe
        uint4 v = *(const uint4*)(hb + (size_t)s * 64 + l8 * 8);
        bool val = (e + oct < deg);
        #pragma unroll
        for (int j = 0; j < 4; ++j) {
            float2 f = bfunpack(((const unsigned int*)&v)[j]);
            acc[2 * j]     += val ? f.x : 0.f;
            acc[2 * j + 1] += val ? f.y : 0.f;
        }
    }
    #pragma unroll
    for (int j = 0; j < 8; ++j) {            // fold 8 octs
        acc[j] += __shfl_xor(acc[j], 8);
        acc[j] += __shfl_xor(acc[j], 16);
        acc[j] += __shfl_xor(acc[j], 32);
    }
    if (oct == 0) {
        float* op = out + (size_t)node * 64 + l8 * 8;
        float4 o0, o1;
        o0.x = fmaf(acc[0], d, bias[l8 * 8 + 0]);
        o0.y = fmaf(acc[1], d, bias[l8 * 8 + 1]);
        o0.z = fmaf(acc[2], d, bias[l8 * 8 + 2]);
        o0.w = fmaf(acc[3], d, bias[l8 * 8 + 3]);
        o1.x = fmaf(acc[4], d, bias[l8 * 8 + 4]);
        o1.y = fmaf(acc[5], d, bias[l8 * 8 + 5]);
        o1.z = fmaf(acc[6], d, bias[l8 * 8 + 6]);
        o1.w = fmaf(acc[7], d, bias[l8 * 8 + 7]);
        *(float4*)(op)     = o0;
        *(float4*)(op + 4) = o1;
    }
}

// ---------------- launcher ----------------

extern "C" void kernel_launch(void* const* d_in, const int* in_sizes, int n_in,
                              void* d_out, int out_size, void* d_ws, size_t ws_size,
                              hipStream_t stream)
{
    const float* x  = (const float*)d_in[0];
    const int*   ei = (const int*)d_in[1];   // [2][E] int32
    const float* W1 = (const float*)d_in[2];
    const float* b1 = (const float*)d_in[3];
    const float* W2 = (const float*)d_in[4];
    const float* b2 = (const float*)d_in[5];
    float* out = (float*)d_out;

    const int N = in_sizes[0] / 128;   // 50000
    const int E = in_sizes[1] / 2;     // 800000
    const int* src = ei;
    const int* dst = ei + E;
    const int partSize = (N + NPART - 1) / NPART;   // 6250

    char* ws = (char*)d_ws;
    size_t off = 0;
    auto alloc = [&](size_t bytes) -> void* {
        void* p = ws + off;
        off += (bytes + 255) & ~(size_t)255;
        return p;
    };
    int*            cnt  = (int*)           alloc((size_t)N * 4);
    unsigned short* ell  = (unsigned short*)alloc((size_t)N * ELL_CAP * 2);
    short*          w1t  = (short*)         alloc((size_t)128 * 128 * 2);
    short*          w2t  = (short*)         alloc((size_t)64 * 128 * 2);
    unsigned short* h1b  = (unsigned short*)alloc((size_t)N * 128 * 2);  // bf16
    unsigned int*   z1b  = (unsigned int*)  alloc((size_t)N * 64 * 4);   // bf16x2
    unsigned short* h2b  = (unsigned short*)alloc((size_t)N * 64 * 2);   // bf16

    hipMemsetAsync(cnt, 0, (size_t)N * 4, stream);
    build_ell_part<<<256 * NPART + 1, 256, 0, stream>>>(
        src, dst, cnt, ell, E, partSize, W1, W2, w1t, w2t);

    // layer 1
    gemm_mfma<128, true><<<(N + 63) / 64, 256, 0, stream>>>(x, w1t, cnt, h1b, N);

    const int nb = (N + 3) / 4;   // 12500
    // 1 real + 4 plain replicas (idempotent) + 1 double-grid replica:
    // T - base = 6*agg1 + 5*launch_overhead; double tops rocprof -> counters.
    for (int r = 0; r < 5; ++r)
        aggregate_l1<<<nb, 256, 0, stream>>>(h1b, ell, cnt, b1, z1b, N, nb);
    aggregate_l1<<<2 * nb, 256, 0, stream>>>(h1b, ell, cnt, b1, z1b, N, nb);

    // layer 2
    gemm_mfma<64, false><<<(N + 63) / 64, 256, 0, stream>>>(z1b, w2t, cnt, h2b, N);
    aggregate_l2<<<(N + 3) / 4, 256, 0, stream>>>(h2b, ell, cnt, b2, out, N);
}

// Round 6
// 297.506 us; speedup vs baseline: 1.3721x; 1.3721x over previous
//
#include <hip/hip_runtime.h>
#include <hip/hip_bf16.h>

// 2-layer GCN on MI355X.
// R11 = targeted measurement #2 + revert of R10's fold regression.
// Measured so far: agg1 = 33us (6.2 TB/s effective = at gather ceiling);
// build+weights-fold = 78-90us vs build-alone <47us (fold = straggler-block
// regression -> REVERTED); budget algebra leaves agg2 ~ 55-70us (2-4x agg1
// at HALF the bytes) as the big reducible unknown. Top-5 exposes only the
// single slowest dispatch type -> this round replicates agg2 x4 (idempotent
// double-grid) to pull its counters above the 44-47us harness fills.
// Pre-commit: T~370-390 + low-BW counters => agg2 gather geometry flawed;
// T~245-260 + hbm>5000 => agg2 fine, mystery is gemm1.

#define ELL_CAP 64   // deg ~ Poisson(16); P(deg>=64) ~ 1e-18
#define NPART 8      // = XCD count

typedef __attribute__((ext_vector_type(8))) short short8;   // 8 bf16 (4 VGPRs)
typedef __attribute__((ext_vector_type(4))) float f32x4;

static __device__ __forceinline__ unsigned short f2bf(float f) {
    unsigned int u = __float_as_uint(f);
    u = (u + 0x7fff + ((u >> 16) & 1)) >> 16;   // round-to-nearest-even
    return (unsigned short)u;
}
static __device__ __forceinline__ float2 bfunpack(unsigned int u) {
    return make_float2(__uint_as_float(u << 16),            // low short  = feat 2i
                       __uint_as_float(u & 0xffff0000u));   // high short = feat 2i+1
}

// ---------------- init: cnt zeroing + both weight transposes ----------------

__global__ void init_misc(const float* __restrict__ W1, const float* __restrict__ W2,
                          short* __restrict__ w1t, short* __restrict__ w2t,
                          int* __restrict__ cnt, int n)
{
    int i = blockIdx.x * blockDim.x + threadIdx.x;
    if (i < 128 * 128) {
        int k = i >> 7, nn = i & 127;
        w1t[nn * 128 + k] = (short)f2bf(W1[i]);
    } else if (i < 128 * 128 + 128 * 64) {
        int j = i - 128 * 128;
        int k = j >> 6, nn = j & 63;
        w2t[nn * 128 + k] = (short)f2bf(W2[j]);
    }
    if (i < n) cnt[i] = 0;
}

// ---------------- XCD-partitioned ELL build (standalone, <47us measured) ---

__global__ __launch_bounds__(256) void build_ell_part(
    const int* __restrict__ src, const int* __restrict__ dst,
    int* __restrict__ cnt, unsigned short* __restrict__ ell, int E, int partSize)
{
    const int part   = blockIdx.x & (NPART - 1);   // = XCD under round-robin
    const int chunk  = blockIdx.x >> 3;
    const int nchunk = gridDim.x >> 3;
    const int lo = part * partSize, hi = lo + partSize;

    const int  E4  = E >> 2;
    const int  per = (E4 + nchunk - 1) / nchunk;
    const int  i1  = min((chunk + 1) * per, E4);
    const int4* __restrict__ d4p = (const int4*)dst;
    const int4* __restrict__ s4p = (const int4*)src;

    for (int i = chunk * per + threadIdx.x; i < i1; i += 256) {
        int4 d4 = d4p[i];
        int4 s4 = s4p[i];
        if (d4.x >= lo && d4.x < hi) {
            int p = atomicAdd(&cnt[d4.x], 1);
            if (p < ELL_CAP) ell[(size_t)d4.x * ELL_CAP + p] = (unsigned short)s4.x;
        }
        if (d4.y >= lo && d4.y < hi) {
            int p = atomicAdd(&cnt[d4.y], 1);
            if (p < ELL_CAP) ell[(size_t)d4.y * ELL_CAP + p] = (unsigned short)s4.y;
        }
        if (d4.z >= lo && d4.z < hi) {
            int p = atomicAdd(&cnt[d4.z], 1);
            if (p < ELL_CAP) ell[(size_t)d4.z * ELL_CAP + p] = (unsigned short)s4.z;
        }
        if (d4.w >= lo && d4.w < hi) {
            int p = atomicAdd(&cnt[d4.w], 1);
            if (p < ELL_CAP) ell[(size_t)d4.w * ELL_CAP + p] = (unsigned short)s4.w;
        }
    }
    if (chunk == 0) {                              // E % 4 tail
        for (int e = (E & ~3) + threadIdx.x; e < E; e += 256) {
            int d = dst[e];
            if (d >= lo && d < hi) {
                int p = atomicAdd(&cnt[d], 1);
                if (p < ELL_CAP) ell[(size_t)d * ELL_CAP + p] = (unsigned short)src[e];
            }
        }
    }
}

// ---------------- MFMA GEMM: Cb[i][j] = bf16(dinv[i]*(A W)[i][j]), row-major

template<int NC, bool AF32>
__global__ __launch_bounds__(256) void gemm_mfma(
    const void* __restrict__ Av, const short* __restrict__ Bt,
    const int* __restrict__ cnt, unsigned short* __restrict__ Cb, int n)
{
    __shared__ short Bs[NC][136];
    const int tid = threadIdx.x;

    #pragma unroll
    for (int i = 0; i < NC / 16; ++i) {      // NC*128 shorts, 16B per thread/iter
        int idx = tid + i * 256;
        int nrow = idx >> 4;
        int kcol = (idx & 15) * 8;
        *(short8*)&Bs[nrow][kcol] = *(const short8*)(Bt + nrow * 128 + kcol);
    }
    __syncthreads();

    const int wave = tid >> 6, lane = tid & 63;
    const int row0 = blockIdx.x * 64 + wave * 16;
    if (row0 >= n) return;
    const int quad = lane >> 4, l16 = lane & 15;

    short8 af[4];
    if (AF32) {
        const float* arow = (const float*)Av + (size_t)(row0 + l16) * 128 + quad * 8;
        #pragma unroll
        for (int kk = 0; kk < 4; ++kk) {
            float4 u = *(const float4*)(arow + kk * 32);
            float4 v = *(const float4*)(arow + kk * 32 + 4);
            short8 f;
            f[0] = (short)f2bf(u.x); f[1] = (short)f2bf(u.y);
            f[2] = (short)f2bf(u.z); f[3] = (short)f2bf(u.w);
            f[4] = (short)f2bf(v.x); f[5] = (short)f2bf(v.y);
            f[6] = (short)f2bf(v.z); f[7] = (short)f2bf(v.w);
            af[kk] = f;
        }
    } else {
        const short* arow = (const short*)Av + (size_t)(row0 + l16) * 128 + quad * 8;
        #pragma unroll
        for (int kk = 0; kk < 4; ++kk)
            af[kk] = *(const short8*)(arow + kk * 32);
    }

    float dv[4];
    #pragma unroll
    for (int r = 0; r < 4; ++r)
        dv[r] = rsqrtf((float)cnt[row0 + quad * 4 + r] + 1.0f);

    #pragma unroll
    for (int t = 0; t < NC / 16; ++t) {
        f32x4 acc = {0.f, 0.f, 0.f, 0.f};
        #pragma unroll
        for (int kk = 0; kk < 4; ++kk) {
            short8 bfr = *(const short8*)&Bs[t * 16 + l16][kk * 32 + quad * 8];
            acc = __builtin_amdgcn_mfma_f32_16x16x32_bf16(af[kk], bfr, acc, 0, 0, 0);
        }
        #pragma unroll
        for (int r = 0; r < 4; ++r) {
            int gr = row0 + quad * 4 + r;
            Cb[(size_t)gr * NC + t * 16 + l16] = f2bf(acc[r] * dv[r]);
        }
    }
}

// ---------------- wide-gather aggregates (R9 structure) ----------------
// L1: one wave per node, 256B rows, dwordx4 gather = 4 edges/instr.
// MEASURED: 33us = 6.2 TB/s effective -> at gather ceiling. Unchanged.

__global__ __launch_bounds__(256) void aggregate_l1(
    const unsigned short* __restrict__ hb,   // [n][128] bf16, dinv-scaled
    const unsigned short* __restrict__ ell,
    const int* __restrict__ cnt, const float* __restrict__ bias,
    unsigned int* __restrict__ z1b, int n)   // [n][64] bf16x2
{
    const int node = blockIdx.x * 4 + (threadIdx.x >> 6);
    if (node >= n) return;
    const int lane = threadIdx.x & 63;
    const int quad = lane >> 4, l16 = lane & 15;

    int deg = cnt[node];
    const float d = rsqrtf((float)deg + 1.0f);
    if (deg > ELL_CAP) deg = ELL_CAP;
    const unsigned short* __restrict__ row = ell + (size_t)node * ELL_CAP;

    float acc[8];
    {   // self term: counted once (quad 0 only)
        uint4 v = *(const uint4*)(hb + (size_t)node * 128 + l16 * 8);
        bool val = (quad == 0);
        #pragma unroll
        for (int j = 0; j < 4; ++j) {
            float2 f = bfunpack(((const unsigned int*)&v)[j]);
            acc[2 * j]     = val ? f.x : 0.f;
            acc[2 * j + 1] = val ? f.y : 0.f;
        }
    }
    const int degR = (deg + 3) & ~3;
    #pragma unroll 2
    for (int e = 0; e < degR; e += 4) {
        unsigned int w0 = *(const unsigned int*)&row[e];       // edges e,e+1
        unsigned int w1 = *(const unsigned int*)&row[e + 2];   // edges e+2,e+3
        unsigned int hw = (quad & 2) ? w1 : w0;
        int s = (quad & 1) ? (int)(hw >> 16) : (int)(hw & 0xffff);
        s = min(s, n - 1);                                      // poison-safe
        uint4 v = *(const uint4*)(hb + (size_t)s * 128 + l16 * 8);
        bool val = (e + quad < deg);
        #pragma unroll
        for (int j = 0; j < 4; ++j) {
            float2 f = bfunpack(((const unsigned int*)&v)[j]);
            acc[2 * j]     += val ? f.x : 0.f;
            acc[2 * j + 1] += val ? f.y : 0.f;
        }
    }
    #pragma unroll
    for (int j = 0; j < 8; ++j) {            // fold 4 quads
        acc[j] += __shfl_xor(acc[j], 16);
        acc[j] += __shfl_xor(acc[j], 32);
    }
    if (quad == 0) {
        unsigned int ow[4];
        #pragma unroll
        for (int j = 0; j < 4; ++j) {
            float bx = bias[l16 * 8 + 2 * j];
            float by = bias[l16 * 8 + 2 * j + 1];
            float ox = fmaxf(fmaf(acc[2 * j],     d, bx), 0.f);
            float oy = fmaxf(fmaf(acc[2 * j + 1], d, by), 0.f);
            ow[j] = (unsigned int)f2bf(ox) | ((unsigned int)f2bf(oy) << 16);
        }
        *(uint4*)&z1b[(size_t)node * 64 + l16 * 4] = *(const uint4*)ow;
    }
}

// L2: one wave per node, 128B rows, dwordx4 gather = 8 edges/instr.
// SUSPECT: budget algebra says ~55-70us (2-4x agg1 at half bytes).
// nb = logical block count; replica grids wrap via modulo (idempotent).

__global__ __launch_bounds__(256) void aggregate_l2(
    const unsigned short* __restrict__ hb,   // [n][64] bf16, dinv-scaled
    const unsigned short* __restrict__ ell,
    const int* __restrict__ cnt, const float* __restrict__ bias,
    float* __restrict__ out, int n, int nb)  // [n][64] fp32
{
    const int lb = (int)(blockIdx.x % (unsigned)nb);
    const int node = lb * 4 + (threadIdx.x >> 6);
    if (node >= n) return;
    const int lane = threadIdx.x & 63;
    const int oct = lane >> 3, l8 = lane & 7;

    int deg = cnt[node];
    const float d = rsqrtf((float)deg + 1.0f);
    if (deg > ELL_CAP) deg = ELL_CAP;
    const unsigned short* __restrict__ row = ell + (size_t)node * ELL_CAP;

    float acc[8];
    {   // self term (oct 0 only)
        uint4 v = *(const uint4*)(hb + (size_t)node * 64 + l8 * 8);
        bool val = (oct == 0);
        #pragma unroll
        for (int j = 0; j < 4; ++j) {
            float2 f = bfunpack(((const unsigned int*)&v)[j]);
            acc[2 * j]     = val ? f.x : 0.f;
            acc[2 * j + 1] = val ? f.y : 0.f;
        }
    }
    const int degR = (deg + 7) & ~7;
    #pragma unroll 2
    for (int e = 0; e < degR; e += 8) {
        uint4 w = *(const uint4*)&row[e];    // edges e..e+7
        unsigned int pw = (oct & 4) ? ((oct & 2) ? w.w : w.z)
                                    : ((oct & 2) ? w.y : w.x);
        int s = (oct & 1) ? (int)(pw >> 16) : (int)(pw & 0xffff);
        s = min(s, n - 1);                   // poison-safe
        uint4 v = *(const uint4*)(hb + (size_t)s * 64 + l8 * 8);
        bool val = (e + oct < deg);
        #pragma unroll
        for (int j = 0; j < 4; ++j) {
            float2 f = bfunpack(((const unsigned int*)&v)[j]);
            acc[2 * j]     += val ? f.x : 0.f;
            acc[2 * j + 1] += val ? f.y : 0.f;
        }
    }
    #pragma unroll
    for (int j = 0; j < 8; ++j) {            // fold 8 octs
        acc[j] += __shfl_xor(acc[j], 8);
        acc[j] += __shfl_xor(acc[j], 16);
        acc[j] += __shfl_xor(acc[j], 32);
    }
    if (oct == 0) {
        float* op = out + (size_t)node * 64 + l8 * 8;
        float4 o0, o1;
        o0.x = fmaf(acc[0], d, bias[l8 * 8 + 0]);
        o0.y = fmaf(acc[1], d, bias[l8 * 8 + 1]);
        o0.z = fmaf(acc[2], d, bias[l8 * 8 + 2]);
        o0.w = fmaf(acc[3], d, bias[l8 * 8 + 3]);
        o1.x = fmaf(acc[4], d, bias[l8 * 8 + 4]);
        o1.y = fmaf(acc[5], d, bias[l8 * 8 + 5]);
        o1.z = fmaf(acc[6], d, bias[l8 * 8 + 6]);
        o1.w = fmaf(acc[7], d, bias[l8 * 8 + 7]);
        *(float4*)(op)     = o0;
        *(float4*)(op + 4) = o1;
    }
}

// ---------------- launcher ----------------

extern "C" void kernel_launch(void* const* d_in, const int* in_sizes, int n_in,
                              void* d_out, int out_size, void* d_ws, size_t ws_size,
                              hipStream_t stream)
{
    const float* x  = (const float*)d_in[0];
    const int*   ei = (const int*)d_in[1];   // [2][E] int32
    const float* W1 = (const float*)d_in[2];
    const float* b1 = (const float*)d_in[3];
    const float* W2 = (const float*)d_in[4];
    const float* b2 = (const float*)d_in[5];
    float* out = (float*)d_out;

    const int N = in_sizes[0] / 128;   // 50000
    const int E = in_sizes[1] / 2;     // 800000
    const int* src = ei;
    const int* dst = ei + E;
    const int partSize = (N + NPART - 1) / NPART;   // 6250

    char* ws = (char*)d_ws;
    size_t off = 0;
    auto alloc = [&](size_t bytes) -> void* {
        void* p = ws + off;
        off += (bytes + 255) & ~(size_t)255;
        return p;
    };
    int*            cnt  = (int*)           alloc((size_t)N * 4);
    unsigned short* ell  = (unsigned short*)alloc((size_t)N * ELL_CAP * 2);
    short*          w1t  = (short*)         alloc((size_t)128 * 128 * 2);
    short*          w2t  = (short*)         alloc((size_t)64 * 128 * 2);
    unsigned short* h1b  = (unsigned short*)alloc((size_t)N * 128 * 2);  // bf16
    unsigned int*   z1b  = (unsigned int*)  alloc((size_t)N * 64 * 4);   // bf16x2
    unsigned short* h2b  = (unsigned short*)alloc((size_t)N * 64 * 2);   // bf16

    init_misc<<<(N + 255) / 256, 256, 0, stream>>>(W1, W2, w1t, w2t, cnt, N);
    build_ell_part<<<256 * NPART, 256, 0, stream>>>(src, dst, cnt, ell, E, partSize);

    // layer 1
    gemm_mfma<128, true><<<(N + 63) / 64, 256, 0, stream>>>(x, w1t, cnt, h1b, N);
    aggregate_l1<<<(N + 3) / 4, 256, 0, stream>>>(h1b, ell, cnt, b1, z1b, N);

    // layer 2
    gemm_mfma<64, false><<<(N + 63) / 64, 256, 0, stream>>>(z1b, w2t, cnt, h2b, N);

    const int nb2 = (N + 3) / 4;   // 12500
    // x4 double-grid replica (idempotent: identical bytes) -> tops the 44-47us
    // harness fills in rocprof top-5, exposing agg2's counters. T-algebra:
    // total = base + 3*agg2 + launch.
    aggregate_l2<<<4 * nb2, 256, 0, stream>>>(h2b, ell, cnt, b2, out, N, nb2);
    aggregate_l2<<<nb2, 256, 0, stream>>>(h2b, ell, cnt, b2, out, N, nb2);
}

// Round 8
// 198.206 us; speedup vs baseline: 2.0595x; 1.5010x over previous
//
#include <hip/hip_runtime.h>
#include <hip/hip_bf16.h>

// 2-layer GCN on MI355X.
// R13 = R12 resubmitted verbatim (R12 bench died to container infra failure,
// not kernel fault). Ledger: build 45, agg1 33 (6.2 TB/s = gather ceiling),
// agg2 26, gemms ~10-12, init 2, launches ~15, harness fill/gaps ~60.
// Change under test: hide gemm1 under build via ZERO-LDS gemm1 (B-fragments
// streamed from L2-hot 32KB w1t, no barrier -> build blocks keep full
// occupancy, fixing R7's 34KB-LDS fusion failure). gemm1 writes UNSCALED
// h1b; agg1 applies dinv[src] per edge (1 cndmask on scalar q + fma = free).
// Same 1-cndmask trim in agg2. nGemm padded to 784 (%8==0) so build
// partition (bid&7) == round-robin XCD id. 6 -> 5 dispatches.
// Predictions: fused ~48-55us, agg1 34-36, agg2 -1-2, total ~180-185.
// Fallback: total >= 192 -> fusion null twice -> ablate build next.

#define ELL_CAP 64   // deg ~ Poisson(16); P(deg>=64) ~ 1e-18
#define NPART 8      // = XCD count
#define NGEMMPAD 784 // ceil(50000/64)=782 padded to %8==0

typedef __attribute__((ext_vector_type(8))) short short8;   // 8 bf16 (4 VGPRs)
typedef __attribute__((ext_vector_type(4))) float f32x4;

static __device__ __forceinline__ unsigned short f2bf(float f) {
    unsigned int u = __float_as_uint(f);
    u = (u + 0x7fff + ((u >> 16) & 1)) >> 16;   // round-to-nearest-even
    return (unsigned short)u;
}
static __device__ __forceinline__ float2 bfunpack(unsigned int u) {
    return make_float2(__uint_as_float(u << 16),            // low short  = feat 2i
                       __uint_as_float(u & 0xffff0000u));   // high short = feat 2i+1
}

// ---------------- init: cnt zeroing + both weight transposes ----------------

__global__ void init_misc(const float* __restrict__ W1, const float* __restrict__ W2,
                          short* __restrict__ w1t, short* __restrict__ w2t,
                          int* __restrict__ cnt, int n)
{
    int i = blockIdx.x * blockDim.x + threadIdx.x;
    if (i < 128 * 128) {
        int k = i >> 7, nn = i & 127;
        w1t[nn * 128 + k] = (short)f2bf(W1[i]);
    } else if (i < 128 * 128 + 128 * 64) {
        int j = i - 128 * 128;
        int k = j >> 6, nn = j & 63;
        w2t[nn * 128 + k] = (short)f2bf(W2[j]);
    }
    if (i < n) cnt[i] = 0;
}

// ---------------- fused: zero-LDS gemm1 + XCD-partitioned ELL build --------
// blocks [0, NGEMMPAD):  gemm1 (no LDS, no barrier): h1b = bf16(x @ W1), UNSCALED
// blocks [NGEMMPAD, +2048): build (part = rel&7 = XCD, chunk = rel>>3)

__global__ __launch_bounds__(256) void fused_b_g1(
    const float* __restrict__ x, const short* __restrict__ w1t,
    const int* __restrict__ src, const int* __restrict__ dst,
    int* __restrict__ cnt, unsigned short* __restrict__ ell,
    unsigned short* __restrict__ h1b, int n, int E, int partSize)
{
    const int bid = blockIdx.x;
    const int tid = threadIdx.x;

    if (bid >= NGEMMPAD) {
        // ---- ELL build ----
        const int rel   = bid - NGEMMPAD;
        const int part  = rel & (NPART - 1);       // == bid&7 == XCD (784%8==0)
        const int chunk = rel >> 3;
        const int nchunk = 256;
        const int lo = part * partSize, hi = lo + partSize;
        const int E4  = E >> 2;
        const int per = (E4 + nchunk - 1) / nchunk;
        const int i1  = min((chunk + 1) * per, E4);
        const int4* __restrict__ d4p = (const int4*)dst;
        const int4* __restrict__ s4p = (const int4*)src;
        for (int i = chunk * per + tid; i < i1; i += 256) {
            int4 d4 = d4p[i];
            int4 s4 = s4p[i];
            if (d4.x >= lo && d4.x < hi) {
                int p = atomicAdd(&cnt[d4.x], 1);
                if (p < ELL_CAP) ell[(size_t)d4.x * ELL_CAP + p] = (unsigned short)s4.x;
            }
            if (d4.y >= lo && d4.y < hi) {
                int p = atomicAdd(&cnt[d4.y], 1);
                if (p < ELL_CAP) ell[(size_t)d4.y * ELL_CAP + p] = (unsigned short)s4.y;
            }
            if (d4.z >= lo && d4.z < hi) {
                int p = atomicAdd(&cnt[d4.z], 1);
                if (p < ELL_CAP) ell[(size_t)d4.z * ELL_CAP + p] = (unsigned short)s4.z;
            }
            if (d4.w >= lo && d4.w < hi) {
                int p = atomicAdd(&cnt[d4.w], 1);
                if (p < ELL_CAP) ell[(size_t)d4.w * ELL_CAP + p] = (unsigned short)s4.w;
            }
        }
        if (chunk == 0) {                          // E % 4 tail
            for (int e = (E & ~3) + tid; e < E; e += 256) {
                int d = dst[e];
                if (d >= lo && d < hi) {
                    int p = atomicAdd(&cnt[d], 1);
                    if (p < ELL_CAP) ell[(size_t)d * ELL_CAP + p] = (unsigned short)src[e];
                }
            }
        }
        return;
    }

    // ---- gemm1, zero-LDS: B fragments streamed from w1t (32KB, L2-hot) ----
    const int wave = tid >> 6, lane = tid & 63;
    const int row0 = bid * 64 + wave * 16;
    if (row0 >= n) return;                         // pad blocks 782,783 exit
    const int quad = lane >> 4, l16 = lane & 15;

    short8 af[4];
    {
        const float* arow = x + (size_t)(row0 + l16) * 128 + quad * 8;
        #pragma unroll
        for (int kk = 0; kk < 4; ++kk) {
            float4 u = *(const float4*)(arow + kk * 32);
            float4 v = *(const float4*)(arow + kk * 32 + 4);
            short8 f;
            f[0] = (short)f2bf(u.x); f[1] = (short)f2bf(u.y);
            f[2] = (short)f2bf(u.z); f[3] = (short)f2bf(u.w);
            f[4] = (short)f2bf(v.x); f[5] = (short)f2bf(v.y);
            f[6] = (short)f2bf(v.z); f[7] = (short)f2bf(v.w);
            af[kk] = f;
        }
    }

    #pragma unroll
    for (int t = 0; t < 8; ++t) {
        f32x4 acc = {0.f, 0.f, 0.f, 0.f};
        #pragma unroll
        for (int kk = 0; kk < 4; ++kk) {
            short8 bfr = *(const short8*)(w1t + (t * 16 + l16) * 128 + kk * 32 + quad * 8);
            acc = __builtin_amdgcn_mfma_f32_16x16x32_bf16(af[kk], bfr, acc, 0, 0, 0);
        }
        #pragma unroll
        for (int r = 0; r < 4; ++r) {
            int gr = row0 + quad * 4 + r;
            h1b[(size_t)gr * 128 + t * 16 + l16] = f2bf(acc[r]);   // UNSCALED
        }
    }
}

// ---------------- MFMA GEMM (layer 2, LDS version, unchanged) --------------
// Cb[i][j] = bf16(dinv[i]*(A W)[i][j]); cnt final here.

template<int NC>
__global__ __launch_bounds__(256) void gemm_mfma(
    const short* __restrict__ A, const short* __restrict__ Bt,
    const int* __restrict__ cnt, unsigned short* __restrict__ Cb, int n)
{
    __shared__ short Bs[NC][136];
    const int tid = threadIdx.x;

    #pragma unroll
    for (int i = 0; i < NC / 16; ++i) {
        int idx = tid + i * 256;
        int nrow = idx >> 4;
        int kcol = (idx & 15) * 8;
        *(short8*)&Bs[nrow][kcol] = *(const short8*)(Bt + nrow * 128 + kcol);
    }
    __syncthreads();

    const int wave = tid >> 6, lane = tid & 63;
    const int row0 = blockIdx.x * 64 + wave * 16;
    if (row0 >= n) return;
    const int quad = lane >> 4, l16 = lane & 15;

    short8 af[4];
    {
        const short* arow = A + (size_t)(row0 + l16) * 128 + quad * 8;
        #pragma unroll
        for (int kk = 0; kk < 4; ++kk)
            af[kk] = *(const short8*)(arow + kk * 32);
    }

    float dv[4];
    #pragma unroll
    for (int r = 0; r < 4; ++r)
        dv[r] = rsqrtf((float)cnt[row0 + quad * 4 + r] + 1.0f);

    #pragma unroll
    for (int t = 0; t < NC / 16; ++t) {
        f32x4 acc = {0.f, 0.f, 0.f, 0.f};
        #pragma unroll
        for (int kk = 0; kk < 4; ++kk) {
            short8 bfr = *(const short8*)&Bs[t * 16 + l16][kk * 32 + quad * 8];
            acc = __builtin_amdgcn_mfma_f32_16x16x32_bf16(af[kk], bfr, acc, 0, 0, 0);
        }
        #pragma unroll
        for (int r = 0; r < 4; ++r) {
            int gr = row0 + quad * 4 + r;
            Cb[(size_t)gr * NC + t * 16 + l16] = f2bf(acc[r] * dv[r]);
        }
    }
}

// ---------------- wide-gather aggregates ----------------
// L1: one wave per node, 256B UNSCALED rows, dwordx4 gather = 4 edges/instr.
// Per-edge dinv[src]: q = rsqrt(cnt[s]+1) masked by validity (1 cndmask),
// accumulate via v_fma (replaces v_add, free). Self term: q = d on quad 0.

__global__ __launch_bounds__(256) void aggregate_l1(
    const unsigned short* __restrict__ hb,   // [n][128] bf16, UNSCALED
    const unsigned short* __restrict__ ell,
    const int* __restrict__ cnt, const float* __restrict__ bias,
    unsigned int* __restrict__ z1b, int n)   // [n][64] bf16x2
{
    const int node = blockIdx.x * 4 + (threadIdx.x >> 6);
    if (node >= n) return;
    const int lane = threadIdx.x & 63;
    const int quad = lane >> 4, l16 = lane & 15;

    int deg = cnt[node];
    const float d = rsqrtf((float)deg + 1.0f);
    if (deg > ELL_CAP) deg = ELL_CAP;
    const unsigned short* __restrict__ row = ell + (size_t)node * ELL_CAP;

    float acc[8];
    {   // self term: q = d on quad 0, else 0 (contributes d^2*h after final *d)
        uint4 v = *(const uint4*)(hb + (size_t)node * 128 + l16 * 8);
        float qs = (quad == 0) ? d : 0.f;
        #pragma unroll
        for (int j = 0; j < 4; ++j) {
            float2 f = bfunpack(((const unsigned int*)&v)[j]);
            acc[2 * j]     = f.x * qs;
            acc[2 * j + 1] = f.y * qs;
        }
    }
    const int degR = (deg + 3) & ~3;
    #pragma unroll 2
    for (int e = 0; e < degR; e += 4) {
        unsigned int w0 = *(const unsigned int*)&row[e];       // edges e,e+1
        unsigned int w1 = *(const unsigned int*)&row[e + 2];   // edges e+2,e+3
        unsigned int hw = (quad & 2) ? w1 : w0;
        int s = (quad & 1) ? (int)(hw >> 16) : (int)(hw & 0xffff);
        s = min(s, n - 1);                                      // poison-safe
        float q = rsqrtf((float)cnt[s] + 1.0f);                 // dinv[src]
        q = (e + quad < deg) ? q : 0.f;                         // 1 cndmask/edge
        uint4 v = *(const uint4*)(hb + (size_t)s * 128 + l16 * 8);
        #pragma unroll
        for (int j = 0; j < 4; ++j) {
            float2 f = bfunpack(((const unsigned int*)&v)[j]);
            acc[2 * j]     = fmaf(f.x, q, acc[2 * j]);
            acc[2 * j + 1] = fmaf(f.y, q, acc[2 * j + 1]);
        }
    }
    #pragma unroll
    for (int j = 0; j < 8; ++j) {            // fold 4 quads
        acc[j] += __shfl_xor(acc[j], 16);
        acc[j] += __shfl_xor(acc[j], 32);
    }
    if (quad == 0) {
        unsigned int ow[4];
        #pragma unroll
        for (int j = 0; j < 4; ++j) {
            float bx = bias[l16 * 8 + 2 * j];
            float by = bias[l16 * 8 + 2 * j + 1];
            float ox = fmaxf(fmaf(acc[2 * j],     d, bx), 0.f);
            float oy = fmaxf(fmaf(acc[2 * j + 1], d, by), 0.f);
            ow[j] = (unsigned int)f2bf(ox) | ((unsigned int)f2bf(oy) << 16);
        }
        *(uint4*)&z1b[(size_t)node * 64 + l16 * 4] = *(const uint4*)ow;
    }
}

// L2: one wave per node, 128B PRE-SCALED rows, dwordx4 gather = 8 edges/instr.
// Validity via 1 cndmask on scalar m + fma (was 8 cndmask + add).

__global__ __launch_bounds__(256) void aggregate_l2(
    const unsigned short* __restrict__ hb,   // [n][64] bf16, dinv-scaled
    const unsigned short* __restrict__ ell,
    const int* __restrict__ cnt, const float* __restrict__ bias,
    float* __restrict__ out, int n)          // [n][64] fp32
{
    const int node = blockIdx.x * 4 + (threadIdx.x >> 6);
    if (node >= n) return;
    const int lane = threadIdx.x & 63;
    const int oct = lane >> 3, l8 = lane & 7;

    int deg = cnt[node];
    const float d = rsqrtf((float)deg + 1.0f);
    if (deg > ELL_CAP) deg = ELL_CAP;
    const unsigned short* __restrict__ row = ell + (size_t)node * ELL_CAP;

    float acc[8];
    {   // self term (oct 0 only)
        uint4 v = *(const uint4*)(hb + (size_t)node * 64 + l8 * 8);
        float ms = (oct == 0) ? 1.f : 0.f;
        #pragma unroll
        for (int j = 0; j < 4; ++j) {
            float2 f = bfunpack(((const unsigned int*)&v)[j]);
            acc[2 * j]     = f.x * ms;
            acc[2 * j + 1] = f.y * ms;
        }
    }
    const int degR = (deg + 7) & ~7;
    #pragma unroll 2
    for (int e = 0; e < degR; e += 8) {
        uint4 w = *(const uint4*)&row[e];    // edges e..e+7
        unsigned int pw = (oct & 4) ? ((oct & 2) ? w.w : w.z)
                                    : ((oct & 2) ? w.y : w.x);
        int s = (oct & 1) ? (int)(pw >> 16) : (int)(pw & 0xffff);
        s = min(s, n - 1);                   // poison-safe
        float m = (e + oct < deg) ? 1.f : 0.f;   // 1 cndmask/edge
        uint4 v = *(const uint4*)(hb + (size_t)s * 64 + l8 * 8);
        #pragma unroll
        for (int j = 0; j < 4; ++j) {
            float2 f = bfunpack(((const unsigned int*)&v)[j]);
            acc[2 * j]     = fmaf(f.x, m, acc[2 * j]);
            acc[2 * j + 1] = fmaf(f.y, m, acc[2 * j + 1]);
        }
    }
    #pragma unroll
    for (int j = 0; j < 8; ++j) {            // fold 8 octs
        acc[j] += __shfl_xor(acc[j], 8);
        acc[j] += __shfl_xor(acc[j], 16);
        acc[j] += __shfl_xor(acc[j], 32);
    }
    if (oct == 0) {
        float* op = out + (size_t)node * 64 + l8 * 8;
        float4 o0, o1;
        o0.x = fmaf(acc[0], d, bias[l8 * 8 + 0]);
        o0.y = fmaf(acc[1], d, bias[l8 * 8 + 1]);
        o0.z = fmaf(acc[2], d, bias[l8 * 8 + 2]);
        o0.w = fmaf(acc[3], d, bias[l8 * 8 + 3]);
        o1.x = fmaf(acc[4], d, bias[l8 * 8 + 4]);
        o1.y = fmaf(acc[5], d, bias[l8 * 8 + 5]);
        o1.z = fmaf(acc[6], d, bias[l8 * 8 + 6]);
        o1.w = fmaf(acc[7], d, bias[l8 * 8 + 7]);
        *(float4*)(op)     = o0;
        *(float4*)(op + 4) = o1;
    }
}

// ---------------- launcher ----------------

extern "C" void kernel_launch(void* const* d_in, const int* in_sizes, int n_in,
                              void* d_out, int out_size, void* d_ws, size_t ws_size,
                              hipStream_t stream)
{
    const float* x  = (const float*)d_in[0];
    const int*   ei = (const int*)d_in[1];   // [2][E] int32
    const float* W1 = (const float*)d_in[2];
    const float* b1 = (const float*)d_in[3];
    const float* W2 = (const float*)d_in[4];
    const float* b2 = (const float*)d_in[5];
    float* out = (float*)d_out;

    const int N = in_sizes[0] / 128;   // 50000
    const int E = in_sizes[1] / 2;     // 800000
    const int* src = ei;
    const int* dst = ei + E;
    const int partSize = (N + NPART - 1) / NPART;   // 6250

    char* ws = (char*)d_ws;
    size_t off = 0;
    auto alloc = [&](size_t bytes) -> void* {
        void* p = ws + off;
        off += (bytes + 255) & ~(size_t)255;
        return p;
    };
    int*            cnt  = (int*)           alloc((size_t)N * 4);
    unsigned short* ell  = (unsigned short*)alloc((size_t)N * ELL_CAP * 2);
    short*          w1t  = (short*)         alloc((size_t)128 * 128 * 2);
    short*          w2t  = (short*)         alloc((size_t)64 * 128 * 2);
    unsigned short* h1b  = (unsigned short*)alloc((size_t)N * 128 * 2);  // bf16
    unsigned int*   z1b  = (unsigned int*)  alloc((size_t)N * 64 * 4);   // bf16x2
    unsigned short* h2b  = (unsigned short*)alloc((size_t)N * 64 * 2);   // bf16

    init_misc<<<(N + 255) / 256, 256, 0, stream>>>(W1, W2, w1t, w2t, cnt, N);

    // build + gemm1 overlapped in one dispatch (independent work, zero LDS)
    fused_b_g1<<<NGEMMPAD + 256 * NPART, 256, 0, stream>>>(
        x, w1t, src, dst, cnt, ell, h1b, N, E, partSize);

    aggregate_l1<<<(N + 3) / 4, 256, 0, stream>>>(h1b, ell, cnt, b1, z1b, N);

    gemm_mfma<64><<<(N + 63) / 64, 256, 0, stream>>>(
        (const short*)z1b, w2t, cnt, h2b, N);

    aggregate_l2<<<(N + 3) / 4, 256, 0, stream>>>(h2b, ell, cnt, b2, out, N);
}